// Round 4
// baseline (390.832 us; speedup 1.0000x reference)
//
#include <hip/hip_runtime.h>
#include <stdint.h>
#include <math.h>

#define C_DIM 128
#define N_TOK 4096
#define NB 4
#define LOG2E 1.4426950408889634f

typedef __attribute__((ext_vector_type(8))) short bf16x8;
typedef __attribute__((ext_vector_type(4))) short bf16x4;
typedef __attribute__((ext_vector_type(4))) float f32x4;

__device__ __forceinline__ unsigned short f2bf(float f) {
  unsigned u = __builtin_bit_cast(unsigned, f);
  unsigned r = (u + 0x7FFFu + ((u >> 16) & 1u)) >> 16;
  return (unsigned short)r;
}
__device__ __forceinline__ float bf2f(unsigned short h) {
  return __builtin_bit_cast(float, ((unsigned)h) << 16);
}

// ---------------- Stage 1: conv1x1(c->2c)+BN -> q [b][n][c] bf16, vT [b][c][n] bf16, max|q|^2 ----------------
__global__ __launch_bounds__(256) void proj_in_kernel(
    const float* __restrict__ x, const float* __restrict__ w_inp,
    const float* __restrict__ b_inp, const float* __restrict__ gamma,
    const float* __restrict__ beta, const float* __restrict__ mean,
    const float* __restrict__ var,
    unsigned short* __restrict__ q, unsigned short* __restrict__ vT,
    int* __restrict__ m2bits) {
  __shared__ char smem[36096];
  unsigned short* xh = (unsigned short*)smem;            // [64][136] bf16 hi
  unsigned short* xl = (unsigned short*)(smem + 17408);  // [64][136] bf16 lo
  float* blkred = (float*)(smem + 35840);                // [64]

  const int tid = threadIdx.x;
  const int b = blockIdx.x >> 6;
  const int n0 = (blockIdx.x & 63) << 6;
  const int lane = tid & 63;
  const int wave = tid >> 6;
  const int l15 = lane & 15, lg = lane >> 4;

  {
    const int c = tid >> 1;
    const int j0 = (tid & 1) * 32;
    const float* src = x + ((size_t)b * C_DIM + c) * N_TOK + n0 + j0;
#pragma unroll
    for (int j = 0; j < 32; j += 4) {
      float4 v4 = *(const float4*)(src + j);
#pragma unroll
      for (int e = 0; e < 4; e++) {
        float f = (&v4.x)[e];
        unsigned short hi = f2bf(f);
        unsigned short lo = f2bf(f - bf2f(hi));
        int n = j0 + j + e;
        xh[n * 136 + c] = hi;
        xl[n * 136 + c] = lo;
      }
    }
  }
  __syncthreads();

  f32x4 acc[4][4];
#pragma unroll
  for (int i = 0; i < 4; i++)
#pragma unroll
    for (int j = 0; j < 4; j++) acc[i][j] = {0.f, 0.f, 0.f, 0.f};

#pragma unroll
  for (int ks = 0; ks < 4; ks++) {
    bf16x8 ah[4], al[4];
#pragma unroll
    for (int ot = 0; ot < 4; ot++) {
      const int o = wave * 64 + ot * 16 + l15;
      const float* wp = w_inp + o * C_DIM + ks * 32 + lg * 8;
      float4 w0 = *(const float4*)wp;
      float4 w1 = *(const float4*)(wp + 4);
#pragma unroll
      for (int e = 0; e < 8; e++) {
        float f = (e < 4) ? (&w0.x)[e] : (&w1.x)[e - 4];
        unsigned short hi = f2bf(f);
        ah[ot][e] = (short)hi;
        al[ot][e] = (short)f2bf(f - bf2f(hi));
      }
    }
#pragma unroll
    for (int nt = 0; nt < 4; nt++) {
      const int off = (nt * 16 + l15) * 136 + ks * 32 + lg * 8;
      bf16x8 bh = *(const bf16x8*)(xh + off);
      bf16x8 bl = *(const bf16x8*)(xl + off);
#pragma unroll
      for (int ot = 0; ot < 4; ot++) {
        acc[ot][nt] = __builtin_amdgcn_mfma_f32_16x16x32_bf16(ah[ot], bh, acc[ot][nt], 0, 0, 0);
        acc[ot][nt] = __builtin_amdgcn_mfma_f32_16x16x32_bf16(ah[ot], bl, acc[ot][nt], 0, 0, 0);
        acc[ot][nt] = __builtin_amdgcn_mfma_f32_16x16x32_bf16(al[ot], bh, acc[ot][nt], 0, 0, 0);
      }
    }
  }
  __syncthreads();

  unsigned short* qT = (unsigned short*)smem;             // [64][136]
  unsigned short* vTl = (unsigned short*)(smem + 17408);  // [128][72]

#pragma unroll
  for (int ot = 0; ot < 4; ot++) {
#pragma unroll
    for (int r = 0; r < 4; r++) {
      const int o = wave * 64 + ot * 16 + lg * 4 + r;
      float A = gamma[o] * rsqrtf(var[o] + 1e-5f);
      float Bo = beta[o] + (b_inp[o] - mean[o]) * A;
#pragma unroll
      for (int nt = 0; nt < 4; nt++) {
        float val = acc[ot][nt][r] * A + Bo;
        unsigned short hv = f2bf(val);
        int n = nt * 16 + l15;
        if (wave < 2) {
          qT[n * 136 + o] = hv;
        } else {
          vTl[(o - 128) * 72 + n] = hv;
        }
      }
    }
  }
  __syncthreads();
  {
    int j = tid >> 2, c0 = (tid & 3) * 32;
    unsigned short* dst = q + ((size_t)b * N_TOK + n0 + j) * C_DIM + c0;
    const unsigned short* s = qT + j * 136 + c0;
#pragma unroll
    for (int i = 0; i < 32; i += 8) *(bf16x8*)(dst + i) = *(const bf16x8*)(s + i);
  }
  {
    int c = tid >> 1, h = (tid & 1) * 32;
    unsigned short* dst = vT + ((size_t)b * C_DIM + c) * N_TOK + n0 + h;
    const unsigned short* s = vTl + c * 72 + h;
#pragma unroll
    for (int i = 0; i < 32; i += 8) *(bf16x8*)(dst + i) = *(const bf16x8*)(s + i);
  }
  // ---- row-norm^2 max -> global atomic (for fixed-m softmax bound) ----
  {
    int row = tid >> 2, qn = tid & 3;
    const unsigned short* qr = qT + row * 136 + qn * 32;
    float s = 0.f;
#pragma unroll
    for (int i = 0; i < 32; i++) {
      float f = bf2f(qr[i]);
      s = fmaf(f, f, s);
    }
    s += __shfl_xor(s, 1);
    s += __shfl_xor(s, 2);
    if ((tid & 3) == 0) blkred[row] = s;
    __syncthreads();
    if (tid < 64) {
      float v = blkred[tid];
      v = fmaxf(v, __shfl_xor(v, 1));
      v = fmaxf(v, __shfl_xor(v, 2));
      v = fmaxf(v, __shfl_xor(v, 4));
      v = fmaxf(v, __shfl_xor(v, 8));
      v = fmaxf(v, __shfl_xor(v, 16));
      v = fmaxf(v, __shfl_xor(v, 32));
      if (tid == 0) atomicMax(m2bits, __float_as_int(v));
    }
  }
}

// ---------------- Stage 2: attention (fixed-m) + fused project_out ----------------
// Block: 32 q-rows, 4 waves = 2 rowgroups x 2 key-halves, grid 512 (2 blocks/CU).
// K fragments loaded DIRECT from global (L2-resident, XCD-swizzled block mapping);
// no staging barriers. Sweep1 (barrier-free): S^T = K*Q^T, p' = exp2, lane-local l,
// unnormalized PV with V in registers. Merge l/PV once, fused project_out.
// Sweep2: recompute S^T per 4-tile group into LDS [32][260] f32, then store atn
// rows as 1KB-contiguous wave stores (HBM write efficiency).
__global__ __launch_bounds__(256) void attn_kernel(
    const unsigned short* __restrict__ q, const unsigned short* __restrict__ vT,
    const float* __restrict__ w_out, const float* __restrict__ b_out,
    float* __restrict__ yout, float* __restrict__ atn,
    const float* __restrict__ m2ptr) {
  __shared__ char smem[55552];
  // sweep1/merge: [32768,37888) per-wave P [16][40] bf16; [37888,38144) statsL;
  //               [38144,55552) ymergeF [2][16][136] f32; [0,32768) yl/ol scratch.
  // sweep2: [0,33280) sbuf [32][260] f32.

  const int tid = threadIdx.x;
  const int lane = tid & 63;
  const int wave = tid >> 6;
  const int rg = wave >> 1;   // row group 0/1
  const int kh = wave & 1;    // key half 0/1
  const int l15 = lane & 15, lg = lane >> 4;
  // XCD-aware swizzle: 512 blocks, 8 XCDs -> 64 consecutive logical blocks per XCD
  const int bid = (int)((blockIdx.x & 7) * 64 + (blockIdx.x >> 3));
  const int b = bid >> 7;
  const int q0 = (bid & 127) << 5;
  const int row0 = q0 + rg * 16;

  const unsigned short* qb = q + (size_t)b * N_TOK * C_DIM;
  const unsigned short* vb = vT + (size_t)b * C_DIM * N_TOK;

  const float scale = 0.08838834764831845f;  // 1/sqrt(128)
  const float ke = scale * LOG2E;
  const float nmk = -(m2ptr[0]) * ke;  // -m * log2e

  // Q fragments (rows row0+l15) -- B operand (Q^T)
  bf16x8 qf[4];
#pragma unroll
  for (int ks = 0; ks < 4; ks++)
    qf[ks] = *(const bf16x8*)(qb + (size_t)(row0 + l15) * C_DIM + ks * 32 + lg * 8);

  // direct-global K A-frag lane base: key = kt*64 + kh*32 + nt*16 + l15, ch = ks*32+lg*8
  const unsigned short* kbase = qb + (size_t)(kh * 32 + l15) * C_DIM + lg * 8;

  unsigned short* pbuf = (unsigned short*)(smem + 32768 + wave * 1280);  // [16][40]
  float* statsL = (float*)(smem + 37888);
  float* ymergeF = (float*)(smem + 38144);
  float* sbuf = (float*)smem;  // [32][260] f32 (sweep2)

  // V direct-load lane base: c = ct*16 + l15, keys kh*32 + lg*8 ..
  const unsigned short* vlane = vb + (size_t)l15 * N_TOK + kh * 32 + lg * 8;

  float lpart = 0.f;
  f32x4 yacc[8];
#pragma unroll
  for (int ct = 0; ct < 8; ct++) yacc[ct] = {0.f, 0.f, 0.f, 0.f};

  bf16x8 vA[8], vB[8];
#pragma unroll
  for (int ct = 0; ct < 8; ct++) vA[ct] = *(const bf16x8*)(vlane + (size_t)ct * 16 * N_TOK);

  unsigned short* pbw0 = pbuf + l15 * 40 + lg * 4;       // nt=0 write slot
  unsigned short* pbw1 = pbuf + l15 * 40 + 16 + lg * 4;  // nt=1 write slot
  const unsigned short* par = pbuf + l15 * 40 + lg * 8;  // A-frag read

  auto sweep1_iter = [&](int kt, bf16x8(&vc)[8], bf16x8(&vn)[8]) {
    if (kt + 1 < 64) {
      const unsigned short* vp = vlane + (size_t)(kt + 1) * 64;
#pragma unroll
      for (int ct = 0; ct < 8; ct++) vn[ct] = *(const bf16x8*)(vp + (size_t)ct * 16 * N_TOK);
    }
    const unsigned short* kp = kbase + (size_t)kt * 64 * C_DIM;
#pragma unroll
    for (int nt = 0; nt < 2; nt++) {
      f32x4 acc = {0.f, 0.f, 0.f, 0.f};
#pragma unroll
      for (int ks = 0; ks < 4; ks++) {
        bf16x8 ak = *(const bf16x8*)(kp + nt * 16 * C_DIM + ks * 32);
        acc = __builtin_amdgcn_mfma_f32_16x16x32_bf16(ak, qf[ks], acc, 0, 0, 0);
      }
      bf16x4 pk;
#pragma unroll
      for (int r = 0; r < 4; r++) {
        float p = __builtin_amdgcn_exp2f(fmaf(acc[r], ke, nmk));
        lpart += p;
        pk[r] = (short)f2bf(p);
      }
      *(bf16x4*)(nt ? pbw1 : pbw0) = pk;
    }
    bf16x8 ap = *(const bf16x8*)par;
#pragma unroll
    for (int ct = 0; ct < 8; ct++)
      yacc[ct] = __builtin_amdgcn_mfma_f32_16x16x32_bf16(ap, vc[ct], yacc[ct], 0, 0, 0);
  };

  for (int kt = 0; kt < 64; kt += 2) {
    sweep1_iter(kt, vA, vB);
    sweep1_iter(kt + 1, vB, vA);
  }

  // ---- merge l across lanes and key-halves ----
  lpart += __shfl_xor(lpart, 16);
  lpart += __shfl_xor(lpart, 32);
  if (lg == 0) statsL[kh * 32 + rg * 16 + l15] = lpart;
  __syncthreads();

  float invl_r[4];
#pragma unroll
  for (int r = 0; r < 4; r++) {
    float ls = statsL[rg * 16 + lg * 4 + r] + statsL[32 + rg * 16 + lg * 4 + r];
    invl_r[r] = 1.0f / ls;
  }
  float invl2;
  {
    float ls = statsL[rg * 16 + l15] + statsL[32 + rg * 16 + l15];
    invl2 = 1.0f / ls;
  }

  // ---- merge PV partials across key-halves, fused project_out ----
  if (kh) {
#pragma unroll
    for (int ct = 0; ct < 8; ct++)
#pragma unroll
      for (int r = 0; r < 4; r++)
        ymergeF[(rg * 16 + lg * 4 + r) * 136 + ct * 16 + l15] = yacc[ct][r];
  }
  __syncthreads();
  if (!kh) {
#pragma unroll
    for (int ct = 0; ct < 8; ct++)
#pragma unroll
      for (int r = 0; r < 4; r++)
        yacc[ct][r] = (yacc[ct][r] + ymergeF[(rg * 16 + lg * 4 + r) * 136 + ct * 16 + l15]) * invl_r[r];

    unsigned short* yl = (unsigned short*)(smem + rg * 16384);  // [16][136] bf16
    float* ol = (float*)(smem + rg * 16384 + 4608);             // [128][20] f32
#pragma unroll
    for (int ct = 0; ct < 8; ct++)
#pragma unroll
      for (int r = 0; r < 4; r++)
        yl[(lg * 4 + r) * 136 + ct * 16 + l15] = f2bf(yacc[ct][r]);

    bf16x8 af[4];
#pragma unroll
    for (int ks = 0; ks < 4; ks++)
      af[ks] = *(const bf16x8*)(yl + l15 * 136 + ks * 32 + lg * 8);

#pragma unroll
    for (int cot = 0; cot < 8; cot++) {
      f32x4 oacc = {0.f, 0.f, 0.f, 0.f};
#pragma unroll
      for (int ks = 0; ks < 4; ks++) {
        const float* wp = w_out + (cot * 16 + l15) * C_DIM + ks * 32 + lg * 8;
        float4 w0 = *(const float4*)wp;
        float4 w1 = *(const float4*)(wp + 4);
        bf16x8 bw;
#pragma unroll
        for (int e = 0; e < 8; e++) bw[e] = (short)f2bf((e < 4) ? (&w0.x)[e] : (&w1.x)[e - 4]);
        oacc = __builtin_amdgcn_mfma_f32_16x16x32_bf16(af[ks], bw, oacc, 0, 0, 0);
      }
      float bo = b_out[cot * 16 + l15];
#pragma unroll
      for (int r = 0; r < 4; r++) ol[(cot * 16 + l15) * 20 + lg * 4 + r] = oacc[r] + bo;
    }
#pragma unroll
    for (int i = 0; i < 2; i++) {
      int co = i * 64 + lane;
      float* dst = yout + ((size_t)b * C_DIM + co) * N_TOK + row0;
      const float* s = ol + co * 20;
#pragma unroll
      for (int jj = 0; jj < 16; jj += 4) *(float4*)(dst + jj) = *(const float4*)(s + jj);
    }
  }
  __syncthreads();  // yl/ol done before sbuf reuse

  // ---- Sweep 2: recompute S^T per 4-tile group, store 1KB-contiguous rows ----
  float* atnb2 = atn + ((size_t)b * N_TOK + q0) * N_TOK;
  float* swr = sbuf + (size_t)(rg * 16 + l15) * 260 + kh * 32 + lg * 4;
  for (int g = 0; g < 16; g++) {
#pragma unroll
    for (int j = 0; j < 4; j++) {
      const int kt = g * 4 + j;
      const unsigned short* kp = kbase + (size_t)kt * 64 * C_DIM;
#pragma unroll
      for (int nt = 0; nt < 2; nt++) {
        f32x4 acc = {0.f, 0.f, 0.f, 0.f};
#pragma unroll
        for (int ks = 0; ks < 4; ks++) {
          bf16x8 ak = *(const bf16x8*)(kp + nt * 16 * C_DIM + ks * 32);
          acc = __builtin_amdgcn_mfma_f32_16x16x32_bf16(ak, qf[ks], acc, 0, 0, 0);
        }
        f32x4 o;
#pragma unroll
        for (int r = 0; r < 4; r++)
          o[r] = __builtin_amdgcn_exp2f(fmaf(acc[r], ke, nmk)) * invl2;
        *(f32x4*)(swr + j * 64 + nt * 16) = o;
      }
    }
    __syncthreads();
    // readout: wave w owns rows w*8..w*8+7; 1KB contiguous per row store
    {
      const float* srcb = sbuf + (size_t)(wave * 8) * 260 + lane * 4;
      float* dstb = atnb2 + (size_t)(wave * 8) * N_TOK + g * 256 + lane * 4;
#pragma unroll
      for (int rr = 0; rr < 8; rr++) {
        f32x4 vv = *(const f32x4*)(srcb + (size_t)rr * 260);
        *(f32x4*)(dstb + (size_t)rr * N_TOK) = vv;
      }
    }
    __syncthreads();
  }
}

extern "C" void kernel_launch(void* const* d_in, const int* in_sizes, int n_in,
                              void* d_out, int out_size, void* d_ws, size_t ws_size,
                              hipStream_t stream) {
  const float* x = (const float*)d_in[0];
  const float* w_inp = (const float*)d_in[1];
  const float* b_inp = (const float*)d_in[2];
  const float* gamma = (const float*)d_in[3];
  const float* beta = (const float*)d_in[4];
  const float* mean = (const float*)d_in[5];
  const float* var = (const float*)d_in[6];
  const float* w_out = (const float*)d_in[7];
  const float* b_out = (const float*)d_in[8];

  float* out = (float*)d_out;
  float* yout = out;                              // [4][128][4096]
  float* atn = out + (size_t)NB * C_DIM * N_TOK;  // [4][4096][4096]

  unsigned short* q = (unsigned short*)d_ws;            // [4][4096][128] bf16
  unsigned short* vT = q + (size_t)NB * N_TOK * C_DIM;  // [4][128][4096] bf16
  int* m2bits = (int*)(vT + (size_t)NB * C_DIM * N_TOK);

  hipMemsetAsync(m2bits, 0, 4, stream);
  proj_in_kernel<<<256, 256, 0, stream>>>(x, w_inp, b_inp, gamma, beta, mean, var, q, vT, m2bits);
  attn_kernel<<<512, 256, 0, stream>>>(q, vT, w_out, b_out, yout, atn, (const float*)m2bits);
}

// Round 5
// 229.020 us; speedup vs baseline: 1.7065x; 1.7065x over previous
//
#include <hip/hip_runtime.h>
#include <stdint.h>
#include <math.h>

#define C_DIM 128
#define N_TOK 4096
#define NB 4
#define LOG2E 1.4426950408889634f

typedef __attribute__((ext_vector_type(8))) short bf16x8;
typedef __attribute__((ext_vector_type(4))) short bf16x4;
typedef __attribute__((ext_vector_type(4))) float f32x4;

__device__ __forceinline__ unsigned short f2bf(float f) {
  unsigned u = __builtin_bit_cast(unsigned, f);
  unsigned r = (u + 0x7FFFu + ((u >> 16) & 1u)) >> 16;
  return (unsigned short)r;
}
__device__ __forceinline__ float bf2f(unsigned short h) {
  return __builtin_bit_cast(float, ((unsigned)h) << 16);
}
__device__ __forceinline__ void gload_lds16(const void* g, void* l) {
  __builtin_amdgcn_global_load_lds((const __attribute__((address_space(1))) void*)g,
                                   (__attribute__((address_space(3))) void*)l,
                                   16, 0, 0);
}

// ---------------- Stage 1: conv1x1(c->2c)+BN -> q [b][n][c] bf16, vT [b][c][n] bf16, max|q|^2 ----------------
__global__ __launch_bounds__(256) void proj_in_kernel(
    const float* __restrict__ x, const float* __restrict__ w_inp,
    const float* __restrict__ b_inp, const float* __restrict__ gamma,
    const float* __restrict__ beta, const float* __restrict__ mean,
    const float* __restrict__ var,
    unsigned short* __restrict__ q, unsigned short* __restrict__ vT,
    int* __restrict__ m2bits) {
  __shared__ char smem[36096];
  unsigned short* xh = (unsigned short*)smem;            // [64][136] bf16 hi
  unsigned short* xl = (unsigned short*)(smem + 17408);  // [64][136] bf16 lo
  float* blkred = (float*)(smem + 35840);                // [64]

  const int tid = threadIdx.x;
  const int b = blockIdx.x >> 6;
  const int n0 = (blockIdx.x & 63) << 6;
  const int lane = tid & 63;
  const int wave = tid >> 6;
  const int l15 = lane & 15, lg = lane >> 4;

  {
    const int c = tid >> 1;
    const int j0 = (tid & 1) * 32;
    const float* src = x + ((size_t)b * C_DIM + c) * N_TOK + n0 + j0;
#pragma unroll
    for (int j = 0; j < 32; j += 4) {
      float4 v4 = *(const float4*)(src + j);
#pragma unroll
      for (int e = 0; e < 4; e++) {
        float f = (&v4.x)[e];
        unsigned short hi = f2bf(f);
        unsigned short lo = f2bf(f - bf2f(hi));
        int n = j0 + j + e;
        xh[n * 136 + c] = hi;
        xl[n * 136 + c] = lo;
      }
    }
  }
  __syncthreads();

  f32x4 acc[4][4];
#pragma unroll
  for (int i = 0; i < 4; i++)
#pragma unroll
    for (int j = 0; j < 4; j++) acc[i][j] = {0.f, 0.f, 0.f, 0.f};

#pragma unroll
  for (int ks = 0; ks < 4; ks++) {
    bf16x8 ah[4], al[4];
#pragma unroll
    for (int ot = 0; ot < 4; ot++) {
      const int o = wave * 64 + ot * 16 + l15;
      const float* wp = w_inp + o * C_DIM + ks * 32 + lg * 8;
      float4 w0 = *(const float4*)wp;
      float4 w1 = *(const float4*)(wp + 4);
#pragma unroll
      for (int e = 0; e < 8; e++) {
        float f = (e < 4) ? (&w0.x)[e] : (&w1.x)[e - 4];
        unsigned short hi = f2bf(f);
        ah[ot][e] = (short)hi;
        al[ot][e] = (short)f2bf(f - bf2f(hi));
      }
    }
#pragma unroll
    for (int nt = 0; nt < 4; nt++) {
      const int off = (nt * 16 + l15) * 136 + ks * 32 + lg * 8;
      bf16x8 bh = *(const bf16x8*)(xh + off);
      bf16x8 bl = *(const bf16x8*)(xl + off);
#pragma unroll
      for (int ot = 0; ot < 4; ot++) {
        acc[ot][nt] = __builtin_amdgcn_mfma_f32_16x16x32_bf16(ah[ot], bh, acc[ot][nt], 0, 0, 0);
        acc[ot][nt] = __builtin_amdgcn_mfma_f32_16x16x32_bf16(ah[ot], bl, acc[ot][nt], 0, 0, 0);
        acc[ot][nt] = __builtin_amdgcn_mfma_f32_16x16x32_bf16(al[ot], bh, acc[ot][nt], 0, 0, 0);
      }
    }
  }
  __syncthreads();

  unsigned short* qT = (unsigned short*)smem;             // [64][136]
  unsigned short* vTl = (unsigned short*)(smem + 17408);  // [128][72]

#pragma unroll
  for (int ot = 0; ot < 4; ot++) {
#pragma unroll
    for (int r = 0; r < 4; r++) {
      const int o = wave * 64 + ot * 16 + lg * 4 + r;
      float A = gamma[o] * rsqrtf(var[o] + 1e-5f);
      float Bo = beta[o] + (b_inp[o] - mean[o]) * A;
#pragma unroll
      for (int nt = 0; nt < 4; nt++) {
        float val = acc[ot][nt][r] * A + Bo;
        unsigned short hv = f2bf(val);
        int n = nt * 16 + l15;
        if (wave < 2) {
          qT[n * 136 + o] = hv;
        } else {
          vTl[(o - 128) * 72 + n] = hv;
        }
      }
    }
  }
  __syncthreads();
  {
    int j = tid >> 2, c0 = (tid & 3) * 32;
    unsigned short* dst = q + ((size_t)b * N_TOK + n0 + j) * C_DIM + c0;
    const unsigned short* s = qT + j * 136 + c0;
#pragma unroll
    for (int i = 0; i < 32; i += 8) *(bf16x8*)(dst + i) = *(const bf16x8*)(s + i);
  }
  {
    int c = tid >> 1, h = (tid & 1) * 32;
    unsigned short* dst = vT + ((size_t)b * C_DIM + c) * N_TOK + n0 + h;
    const unsigned short* s = vTl + c * 72 + h;
#pragma unroll
    for (int i = 0; i < 32; i += 8) *(bf16x8*)(dst + i) = *(const bf16x8*)(s + i);
  }
  // ---- row-norm^2 max -> global atomic (for fixed-m softmax bound) ----
  {
    int row = tid >> 2, qn = tid & 3;
    const unsigned short* qr = qT + row * 136 + qn * 32;
    float s = 0.f;
#pragma unroll
    for (int i = 0; i < 32; i++) {
      float f = bf2f(qr[i]);
      s = fmaf(f, f, s);
    }
    s += __shfl_xor(s, 1);
    s += __shfl_xor(s, 2);
    if ((tid & 3) == 0) blkred[row] = s;
    __syncthreads();
    if (tid < 64) {
      float v = blkred[tid];
      v = fmaxf(v, __shfl_xor(v, 1));
      v = fmaxf(v, __shfl_xor(v, 2));
      v = fmaxf(v, __shfl_xor(v, 4));
      v = fmaxf(v, __shfl_xor(v, 8));
      v = fmaxf(v, __shfl_xor(v, 16));
      v = fmaxf(v, __shfl_xor(v, 32));
      if (tid == 0) atomicMax(m2bits, __float_as_int(v));
    }
  }
}

// ---------------- Stage 2: attention (fixed-m) + fused project_out ----------------
// Round-3 compute structure (LDS-staged K dbuf, V in registers, fixed-m softmax,
// lane-local l) + round-4 store layout (LDS-buffered 256-key groups, 1KB-contiguous
// non-temporal atn stores).
__global__ __launch_bounds__(256) void attn_kernel(
    const unsigned short* __restrict__ q, const unsigned short* __restrict__ vT,
    const float* __restrict__ w_out, const float* __restrict__ b_out,
    float* __restrict__ yout, float* __restrict__ atn,
    const float* __restrict__ m2ptr) {
  __shared__ char smem[66304];
  // [0,32768): K dbuf (2 x 16KB)  (also yl/ol scratch during project_out)
  // [32768,66048): union: sweep1 per-wave P [16][40] bf16 (32768..37888),
  //                merge ymergeF [2][16][136] f32 (38144..55552),
  //                sweep2 sbuf [32][260] f32 (32768..66048)
  // [66048,66304): statsL (64 f32)

  const int tid = threadIdx.x;
  const int lane = tid & 63;
  const int wave = tid >> 6;
  const int rg = wave >> 1;   // row group 0/1
  const int kh = wave & 1;    // key half 0/1
  const int l15 = lane & 15, lg = lane >> 4, l7 = lane & 7;
  const int b = blockIdx.x >> 7;
  const int q0 = (blockIdx.x & 127) << 5;
  const int row0 = q0 + rg * 16;

  const unsigned short* qb = q + (size_t)b * N_TOK * C_DIM;
  const unsigned short* vb = vT + (size_t)b * C_DIM * N_TOK;

  const float scale = 0.08838834764831845f;  // 1/sqrt(128)
  const float ke = scale * LOG2E;
  const float nmk = -(m2ptr[0]) * ke;  // -m * log2e

  // Q fragments (rows row0+l15) -- B operand (Q^T)
  bf16x8 qf[4];
#pragma unroll
  for (int ks = 0; ks < 4; ks++)
    qf[ks] = *(const bf16x8*)(qb + (size_t)(row0 + l15) * C_DIM + ks * 32 + lg * 8);

  int koff[4];  // swizzled within-row byte offset for K reads
#pragma unroll
  for (int ks = 0; ks < 4; ks++) koff[ks] = (ks * 64 + lg * 16) ^ (l7 * 16);
  const int krow = l15 * 256;  // K row byte base within nt-group

  auto stageK = [&](int kt, int buf) {
    char* base = smem + buf * 16384;
#pragma unroll
    for (int i = 0; i < 4; i++) {
      int lin = i * 256 + tid;
      int key = lin >> 4;
      int c = ((lin & 15) * 8) ^ ((key & 7) * 8);
      gload_lds16(qb + (size_t)(kt * 64 + key) * C_DIM + c, base + lin * 16);
    }
  };

  unsigned short* pbuf = (unsigned short*)(smem + 32768 + wave * 1280);  // [16][40]
  float* ymergeF = (float*)(smem + 38144);
  float* statsL = (float*)(smem + 66048);
  float* sbuf = (float*)(smem + 32768);  // [32][260] f32 (sweep2)

  // V direct-load lane base: c = ct*16 + l15, keys kh*32 + lg*8 ..
  const unsigned short* vlane = vb + (size_t)l15 * N_TOK + kh * 32 + lg * 8;

  float lpart = 0.f;
  f32x4 yacc[8];
#pragma unroll
  for (int ct = 0; ct < 8; ct++) yacc[ct] = {0.f, 0.f, 0.f, 0.f};

  bf16x8 vA[8], vB[8];
  // prologue: stage K tile 0, load V tile 0
  stageK(0, 0);
#pragma unroll
  for (int ct = 0; ct < 8; ct++) vA[ct] = *(const bf16x8*)(vlane + (size_t)ct * 16 * N_TOK);
  __syncthreads();

  unsigned short* pbw0 = pbuf + l15 * 40 + lg * 4;       // nt=0 write slot
  unsigned short* pbw1 = pbuf + l15 * 40 + 16 + lg * 4;  // nt=1 write slot
  const unsigned short* par = pbuf + l15 * 40 + lg * 8;  // A-frag read

  auto sweep1_iter = [&](int kt, bf16x8(&vc)[8], bf16x8(&vn)[8]) {
    if (kt + 1 < 64) {
      stageK(kt + 1, (kt + 1) & 1);
      const unsigned short* vp = vlane + (size_t)(kt + 1) * 64;
#pragma unroll
      for (int ct = 0; ct < 8; ct++) vn[ct] = *(const bf16x8*)(vp + (size_t)ct * 16 * N_TOK);
    }
    const char* kb = smem + (kt & 1) * 16384;
#pragma unroll
    for (int nt = 0; nt < 2; nt++) {
      f32x4 acc = {0.f, 0.f, 0.f, 0.f};
#pragma unroll
      for (int ks = 0; ks < 4; ks++) {
        bf16x8 ak = *(const bf16x8*)(kb + (kh * 2 + nt) * 4096 + krow + koff[ks]);
        acc = __builtin_amdgcn_mfma_f32_16x16x32_bf16(ak, qf[ks], acc, 0, 0, 0);
      }
      bf16x4 pk;
#pragma unroll
      for (int r = 0; r < 4; r++) {
        float p = __builtin_amdgcn_exp2f(fmaf(acc[r], ke, nmk));
        lpart += p;
        pk[r] = (short)f2bf(p);
      }
      *(bf16x4*)(nt ? pbw1 : pbw0) = pk;
    }
    bf16x8 ap = *(const bf16x8*)par;
#pragma unroll
    for (int ct = 0; ct < 8; ct++)
      yacc[ct] = __builtin_amdgcn_mfma_f32_16x16x32_bf16(ap, vc[ct], yacc[ct], 0, 0, 0);
    __syncthreads();
  };

  for (int kt = 0; kt < 64; kt += 2) {
    sweep1_iter(kt, vA, vB);
    sweep1_iter(kt + 1, vB, vA);
  }

  // ---- merge l across lanes and key-halves ----
  lpart += __shfl_xor(lpart, 16);
  lpart += __shfl_xor(lpart, 32);
  if (lg == 0) statsL[kh * 32 + rg * 16 + l15] = lpart;
  __syncthreads();

  float invl_r[4];
#pragma unroll
  for (int r = 0; r < 4; r++) {
    float ls = statsL[rg * 16 + lg * 4 + r] + statsL[32 + rg * 16 + lg * 4 + r];
    invl_r[r] = 1.0f / ls;
  }
  float invl2;
  {
    float ls = statsL[rg * 16 + l15] + statsL[32 + rg * 16 + l15];
    invl2 = 1.0f / ls;
  }

  // ---- merge PV partials across key-halves, fused project_out ----
  if (kh) {
#pragma unroll
    for (int ct = 0; ct < 8; ct++)
#pragma unroll
      for (int r = 0; r < 4; r++)
        ymergeF[(rg * 16 + lg * 4 + r) * 136 + ct * 16 + l15] = yacc[ct][r];
  }
  __syncthreads();
  if (!kh) {
#pragma unroll
    for (int ct = 0; ct < 8; ct++)
#pragma unroll
      for (int r = 0; r < 4; r++)
        yacc[ct][r] = (yacc[ct][r] + ymergeF[(rg * 16 + lg * 4 + r) * 136 + ct * 16 + l15]) * invl_r[r];

    unsigned short* yl = (unsigned short*)(smem + rg * 16384);  // [16][136] bf16
    float* ol = (float*)(smem + rg * 16384 + 4608);             // [128][20] f32
#pragma unroll
    for (int ct = 0; ct < 8; ct++)
#pragma unroll
      for (int r = 0; r < 4; r++)
        yl[(lg * 4 + r) * 136 + ct * 16 + l15] = f2bf(yacc[ct][r]);

    bf16x8 af[4];
#pragma unroll
    for (int ks = 0; ks < 4; ks++)
      af[ks] = *(const bf16x8*)(yl + l15 * 136 + ks * 32 + lg * 8);

#pragma unroll
    for (int cot = 0; cot < 8; cot++) {
      f32x4 oacc = {0.f, 0.f, 0.f, 0.f};
#pragma unroll
      for (int ks = 0; ks < 4; ks++) {
        const float* wp = w_out + (cot * 16 + l15) * C_DIM + ks * 32 + lg * 8;
        float4 w0 = *(const float4*)wp;
        float4 w1 = *(const float4*)(wp + 4);
        bf16x8 bw;
#pragma unroll
        for (int e = 0; e < 8; e++) bw[e] = (short)f2bf((e < 4) ? (&w0.x)[e] : (&w1.x)[e - 4]);
        oacc = __builtin_amdgcn_mfma_f32_16x16x32_bf16(af[ks], bw, oacc, 0, 0, 0);
      }
      float bo = b_out[cot * 16 + l15];
#pragma unroll
      for (int r = 0; r < 4; r++) ol[(cot * 16 + l15) * 20 + lg * 4 + r] = oacc[r] + bo;
    }
#pragma unroll
    for (int i = 0; i < 2; i++) {
      int co = i * 64 + lane;
      float* dst = yout + ((size_t)b * C_DIM + co) * N_TOK + row0;
      const float* s = ol + co * 20;
#pragma unroll
      for (int jj = 0; jj < 16; jj += 4) *(float4*)(dst + jj) = *(const float4*)(s + jj);
    }
  }
  __syncthreads();  // yl/ol + ymergeF done before kbuf/sbuf reuse

  // ---- Sweep 2: recompute S^T per 256-key group into LDS, 1KB-contiguous NT stores ----
  stageK(0, 0);
  __syncthreads();
  float* swr = sbuf + (size_t)(rg * 16 + l15) * 260 + kh * 32 + lg * 4;
  float* atnb2 = atn + ((size_t)b * N_TOK + q0) * N_TOK;
  for (int g = 0; g < 16; g++) {
#pragma unroll
    for (int j = 0; j < 4; j++) {
      const int kt = g * 4 + j;
      if (kt + 1 < 64) stageK(kt + 1, (kt + 1) & 1);
      const char* kb = smem + (kt & 1) * 16384;
#pragma unroll
      for (int nt = 0; nt < 2; nt++) {
        f32x4 acc = {0.f, 0.f, 0.f, 0.f};
#pragma unroll
        for (int ks = 0; ks < 4; ks++) {
          bf16x8 ak = *(const bf16x8*)(kb + (kh * 2 + nt) * 4096 + krow + koff[ks]);
          acc = __builtin_amdgcn_mfma_f32_16x16x32_bf16(ak, qf[ks], acc, 0, 0, 0);
        }
        f32x4 o;
#pragma unroll
        for (int r = 0; r < 4; r++)
          o[r] = __builtin_amdgcn_exp2f(fmaf(acc[r], ke, nmk)) * invl2;
        *(f32x4*)(swr + j * 64 + nt * 16) = o;
      }
      __syncthreads();
    }
    // readout: wave w owns rows w*8..w*8+7; 1KB contiguous non-temporal store per row
    {
      const float* srcb = sbuf + (size_t)(wave * 8) * 260 + lane * 4;
      float* dstb = atnb2 + (size_t)(wave * 8) * N_TOK + g * 256 + lane * 4;
#pragma unroll
      for (int rr = 0; rr < 8; rr++) {
        f32x4 vv = *(const f32x4*)(srcb + (size_t)rr * 260);
        __builtin_nontemporal_store(vv, (f32x4*)(dstb + (size_t)rr * N_TOK));
      }
    }
    __syncthreads();
  }
}

extern "C" void kernel_launch(void* const* d_in, const int* in_sizes, int n_in,
                              void* d_out, int out_size, void* d_ws, size_t ws_size,
                              hipStream_t stream) {
  const float* x = (const float*)d_in[0];
  const float* w_inp = (const float*)d_in[1];
  const float* b_inp = (const float*)d_in[2];
  const float* gamma = (const float*)d_in[3];
  const float* beta = (const float*)d_in[4];
  const float* mean = (const float*)d_in[5];
  const float* var = (const float*)d_in[6];
  const float* w_out = (const float*)d_in[7];
  const float* b_out = (const float*)d_in[8];

  float* out = (float*)d_out;
  float* yout = out;                              // [4][128][4096]
  float* atn = out + (size_t)NB * C_DIM * N_TOK;  // [4][4096][4096]

  unsigned short* q = (unsigned short*)d_ws;            // [4][4096][128] bf16
  unsigned short* vT = q + (size_t)NB * N_TOK * C_DIM;  // [4][128][4096] bf16
  int* m2bits = (int*)(vT + (size_t)NB * C_DIM * N_TOK);

  hipMemsetAsync(m2bits, 0, 4, stream);
  proj_in_kernel<<<256, 256, 0, stream>>>(x, w_inp, b_inp, gamma, beta, mean, var, q, vT, m2bits);
  attn_kernel<<<512, 256, 0, stream>>>(q, vT, w_out, b_out, yout, atn, (const float*)m2bits);
}